// Round 6
// baseline (297.134 us; speedup 1.0000x reference)
//
#include <hip/hip_runtime.h>
#include <hip/hip_bf16.h>

typedef __attribute__((ext_vector_type(8))) short bf16x8;
typedef __attribute__((ext_vector_type(4))) float f32x4;
typedef __attribute__((ext_vector_type(8))) unsigned short u16x8;

static __device__ __forceinline__ unsigned short bf16bits(float v) {
    __hip_bfloat16 h = __float2bfloat16(v);
    return *(unsigned short*)&h;
}

// ---- weight prep: fc1 K-permuted (k' = o*36+t) + zero-pad 360->384; fc2 ----
__global__ __launch_bounds__(256) void prep_weights(
    const float* __restrict__ fc1w, const float* __restrict__ fc2w,
    __hip_bfloat16* __restrict__ w1o, __hip_bfloat16* __restrict__ w2o)
{
    int id = blockIdx.x * 256 + threadIdx.x;
    if (id < 256 * 384) {
        int n = id / 384, k2 = id - n * 384;      // k2 = o*36 + t
        float v = 0.0f;
        if (k2 < 360) {
            int o = k2 / 36, t = k2 - o * 36;
            v = fc1w[n * 360 + t * 10 + o];
        }
        w1o[id] = __float2bfloat16(v);
    } else {
        int id2 = id - 256 * 384;
        if (id2 < 64 * 256) w2o[id2] = __float2bfloat16(fc2w[id2]);
    }
}

// =================== fused: std + MFMA convs + fc1 + fc2 + head ============
// 32 samples/block, 256 thr, 4096 blocks, LDS 51320 B -> 3 blocks/CU.
// Layouts (bf16 staging zero-initialized so MFMA K-pad lanes are exact 0):
//   P  @0     : 2 tiles x [16 smp][41 pos][8 ch]        = 20992 B [dead after conv2]
//   T  @0     : [32 smp][264 bf16] stride 528B          = 16896 B [over dead P]
//   SD @20992 : 2 tiles x [16 smp][43 pos][8 ch]        = 22016 B [dead after conv1]
//   F  @20992 : [32 smp][392 k'] stride 784B            = 25088 B [over dead SD]
//   cw @46080 : 210 f32 conv consts
//   b1 @46920 : 256 f32 fc1 bias | b2 @47944 : 64 f32 fc2 bias
//   pw @48200 : 768 f32 head W   | pb @51272 : 12 f32 head bias
#define P_BASE  0
#define P_TILE  10496
#define P_SSTR  656
#define SD_BASE 20992
#define SD_TILE 11008
#define SD_SSTR 688
#define F_BASE  20992
#define F_RSTR  784
#define CW_OFF  46080
#define B1B_OFF 46920
#define B2B_OFF 47944
#define PW_OFF  48200
#define PB_OFF  51272
#define T_BASE  0
#define T_SSTR  528
__global__ __launch_bounds__(256, 3) void fused_kernel(
    const float* __restrict__ sig,
    const float* __restrict__ c1w_g, const float* __restrict__ c1b_g,
    const float* __restrict__ c2w_g, const float* __restrict__ c2b_g,
    const __hip_bfloat16* __restrict__ W1, const __hip_bfloat16* __restrict__ W2,
    const float* __restrict__ fc1b, const float* __restrict__ fc2b,
    const float* __restrict__ pw, const float* __restrict__ pb,
    float* __restrict__ out)
{
    __shared__ __align__(16) unsigned char smem[51320];
    float* cw  = (float*)(smem + CW_OFF);
    float* bb1 = (float*)(smem + B1B_OFF);
    float* bb2 = (float*)(smem + B2B_OFF);
    float* pwl = (float*)(smem + PW_OFF);
    float* pbl = (float*)(smem + PB_OFF);

    const int tid  = threadIdx.x;
    const int blk  = blockIdx.x;
    const int wv   = tid >> 6;
    const int lane = tid & 63;
    const int ml   = lane & 15;
    const int kg   = lane >> 4;

    // phase -1: zero P+SD (MFMA K-pad safety) + stage ALL consts
    {
        f32x4 z = {0.f, 0.f, 0.f, 0.f};
        for (int i = tid; i < 2688; i += 256)
            *(f32x4*)(smem + i * 16) = z;
        if (tid < 210) {
            float v;
            if (tid < 45)       v = c1w_g[tid];
            else if (tid < 50)  v = c1b_g[tid - 45];
            else if (tid < 200) v = c2w_g[tid - 50];
            else                v = c2b_g[tid - 200];
            cw[tid] = v;
        }
        bb1[tid] = fc1b[tid];
        if (tid < 64) bb2[tid] = fc2b[tid];
        for (int i = tid; i < 768; i += 256) pwl[i] = pw[i];
        if (tid < 12) pbl[tid] = pb[tid];
    }
    __syncthreads();

    // phase 0: running std (w=10, ddof=1), sliding. 192 threads: (s, c, half)
    if (tid < 192) {
        int s = tid / 6, r = tid - s * 6;
        int c = r >> 1, h = r & 1;
        int j0 = h * 20;
        const float* g = sig + (size_t)blk * 4800 + s * 150 + c;
        float x[30];
        #pragma unroll
        for (int j = 0; j < 30; ++j) x[j] = g[(j0 + j) * 3];
        float sum = 0.f, sq = 0.f;
        #pragma unroll
        for (int j = 0; j < 10; ++j) { sum += x[j]; sq += x[j] * x[j]; }
        unsigned char* sd = smem + SD_BASE + (s >> 4) * SD_TILE + (s & 15) * SD_SSTR + c * 2;
        #pragma unroll
        for (int i = 0; i < 20; ++i) {
            float var = (sq - sum * sum * 0.1f) * (1.0f / 9.0f);
            *(unsigned short*)(sd + (j0 + i) * 16) = bf16bits(sqrtf(fmaxf(var, 0.f)));
            if (i < 19) {
                float d = x[i + 10] - x[i];
                sq  += d * (x[i + 10] + x[i]);
                sum += d;
            }
        }
    }

    // conv weight B-fragments (regs, built once; K padded with exact zeros)
    bf16x8 B1f, B2f;
    #pragma unroll
    for (int j = 0; j < 8; ++j) {
        float v1 = (ml < 5  && kg < 3 && j < 3) ? cw[ml * 9 + j * 3 + kg] : 0.f;
        float v2 = (ml < 10 && kg < 3 && j < 5) ? cw[50 + ml * 15 + j * 3 + kg] : 0.f;
        B1f[j] = (short)bf16bits(v1);
        B2f[j] = (short)bf16bits(v2);
    }
    const float c1bias = (ml < 5)  ? cw[45 + ml]  : 0.f;
    const float c2bias = (ml < 10) ? cw[200 + ml] : 0.f;
    __syncthreads();

    // phase 1: conv1 (5,3,3)+relu via MFMA. wave -> (tile, t-half of 38)
    {
        const int tile = wv >> 1, half = wv & 1;
        const unsigned char* sdb = smem + SD_BASE + tile * SD_TILE + ml * SD_SSTR;
        unsigned char* pbuf = smem + P_BASE + tile * P_TILE + ml * 2;
        #pragma unroll
        for (int it = 0; it < 19; ++it) {
            int t = half * 19 + it;
            bf16x8 a = *(const bf16x8*)(sdb + (t + kg) * 16);
            f32x4 acc = {0.f, 0.f, 0.f, 0.f};
            acc = __builtin_amdgcn_mfma_f32_16x16x32_bf16(a, B1f, acc, 0, 0, 0);
            if (ml < 5) {
                #pragma unroll
                for (int i = 0; i < 4; ++i) {
                    float v = fmaxf(acc[i] + c1bias, 0.f);
                    *(unsigned short*)(pbuf + (kg * 4 + i) * P_SSTR + t * 16) = bf16bits(v);
                }
            }
        }
    }
    __syncthreads();

    // zero F k'-tail cols [360,392) (over dead SD region)
    if (tid < 128) {
        f32x4 z = {0.f, 0.f, 0.f, 0.f};
        int r = tid >> 2, q = tid & 3;
        *(f32x4*)(smem + F_BASE + r * F_RSTR + 720 + q * 16) = z;
    }

    // phase 2: conv2 (10,5,3)+relu via MFMA -> F[s][o*36+t]
    {
        const int tile = wv >> 1, half = wv & 1;
        const unsigned char* pbr = smem + P_BASE + tile * P_TILE + ml * P_SSTR;
        unsigned char* fb = smem + F_BASE + tile * 16 * F_RSTR + ml * 72;
        #pragma unroll
        for (int it = 0; it < 18; ++it) {
            int t = half * 18 + it;
            bf16x8 a = *(const bf16x8*)(pbr + (t + kg) * 16);
            f32x4 acc = {0.f, 0.f, 0.f, 0.f};
            acc = __builtin_amdgcn_mfma_f32_16x16x32_bf16(a, B2f, acc, 0, 0, 0);
            if (ml < 10) {
                #pragma unroll
                for (int i = 0; i < 4; ++i) {
                    float v = fmaxf(acc[i] + c2bias, 0.f);
                    *(unsigned short*)(fb + (kg * 4 + i) * F_RSTR + t * 2) = bf16bits(v);
                }
            }
        }
    }
    __syncthreads();   // F complete; P now dead -> T may be written

    // ---- fc1: 256x384 @ 32 samples. A = W1 rows (global, L2-hot),
    //      B = activations (regs from F). Wave w owns rows [w*64, w*64+64).
    bf16x8 bfr[12][2];
    #pragma unroll
    for (int kk = 0; kk < 12; ++kk) {
        bfr[kk][0] = *(const bf16x8*)(smem + F_BASE + ml * F_RSTR + kk * 64 + kg * 16);
        bfr[kk][1] = *(const bf16x8*)(smem + F_BASE + (16 + ml) * F_RSTR + kk * 64 + kg * 16);
    }
    {
        const int rowbase = wv * 64;
        #pragma unroll
        for (int rt = 0; rt < 4; ++rt) {
            int row0 = rowbase + rt * 16;
            const __hip_bfloat16* wsrc = W1 + (size_t)(row0 + ml) * 384 + kg * 8;
            f32x4 a0 = {0.f, 0.f, 0.f, 0.f}, a1 = {0.f, 0.f, 0.f, 0.f};
            #pragma unroll
            for (int kk = 0; kk < 12; ++kk) {
                bf16x8 wf = *(const bf16x8*)(wsrc + kk * 32);
                a0 = __builtin_amdgcn_mfma_f32_16x16x32_bf16(wf, bfr[kk][0], a0, 0, 0, 0);
                a1 = __builtin_amdgcn_mfma_f32_16x16x32_bf16(wf, bfr[kk][1], a1, 0, 0, 0);
            }
            float4 b4 = *(const float4*)(bb1 + row0 + kg * 4);
            {
                unsigned int p0 = (unsigned int)bf16bits(fmaxf(a0[0] + b4.x, 0.f))
                                | ((unsigned int)bf16bits(fmaxf(a0[1] + b4.y, 0.f)) << 16);
                unsigned int p1 = (unsigned int)bf16bits(fmaxf(a0[2] + b4.z, 0.f))
                                | ((unsigned int)bf16bits(fmaxf(a0[3] + b4.w, 0.f)) << 16);
                uint2 pk = {p0, p1};
                *(uint2*)(smem + T_BASE + ml * T_SSTR + (row0 + kg * 4) * 2) = pk;
            }
            {
                unsigned int p0 = (unsigned int)bf16bits(fmaxf(a1[0] + b4.x, 0.f))
                                | ((unsigned int)bf16bits(fmaxf(a1[1] + b4.y, 0.f)) << 16);
                unsigned int p1 = (unsigned int)bf16bits(fmaxf(a1[2] + b4.z, 0.f))
                                | ((unsigned int)bf16bits(fmaxf(a1[3] + b4.w, 0.f)) << 16);
                uint2 pk = {p0, p1};
                *(uint2*)(smem + T_BASE + (16 + ml) * T_SSTR + (row0 + kg * 4) * 2) = pk;
            }
        }
    }
    __syncthreads();   // T complete

    // ---- fc2 + head: waves 0,1 each own one 16-sample tile ----
    if (wv < 2) {
        f32x4 acc2[4];
        #pragma unroll
        for (int t2 = 0; t2 < 4; ++t2) acc2[t2] = f32x4{0.f, 0.f, 0.f, 0.f};
        #pragma unroll
        for (int kk = 0; kk < 8; ++kk) {
            bf16x8 pf = *(const bf16x8*)(smem + T_BASE + (wv * 16 + ml) * T_SSTR
                                         + (kk * 32 + kg * 8) * 2);
            #pragma unroll
            for (int t2 = 0; t2 < 4; ++t2) {
                bf16x8 a2 = *(const bf16x8*)(W2 + (t2 * 16 + ml) * 256 + kk * 32 + kg * 8);
                acc2[t2] = __builtin_amdgcn_mfma_f32_16x16x32_bf16(a2, pf, acc2[t2], 0, 0, 0);
            }
        }
        float h[16];
        #pragma unroll
        for (int t2 = 0; t2 < 4; ++t2) {
            float4 b4 = *(const float4*)(bb2 + t2 * 16 + kg * 4);
            #pragma unroll
            for (int i = 0; i < 4; ++i)
                h[t2 * 4 + i] = fmaxf(acc2[t2][i] + ((const float*)&b4)[i], 0.f);
        }
        float lg[12];
        #pragma unroll
        for (int j = 0; j < 12; ++j) {
            float s = 0.f;
            #pragma unroll
            for (int t2 = 0; t2 < 4; ++t2) {
                float4 wv4 = *(const float4*)(pwl + j * 64 + t2 * 16 + kg * 4);
                s += wv4.x * h[t2 * 4 + 0] + wv4.y * h[t2 * 4 + 1]
                   + wv4.z * h[t2 * 4 + 2] + wv4.w * h[t2 * 4 + 3];
            }
            lg[j] = s;
        }
        #pragma unroll
        for (int j = 0; j < 12; ++j) {
            lg[j] += __shfl_xor(lg[j], 16);
            lg[j] += __shfl_xor(lg[j], 32);
            lg[j] += pbl[j];
        }
        float m = lg[0];
        #pragma unroll
        for (int j = 1; j < 12; ++j) m = fmaxf(m, lg[j]);
        float e = 0.f;
        #pragma unroll
        for (int j = 0; j < 12; ++j) e += __expf(lg[j] - m);
        float lse = m + __logf(e);
        if (kg == 0) {
            float* op = out + (size_t)(blk * 32 + wv * 16 + ml) * 12;
            float4 o0 = {lg[0] - lse, lg[1] - lse, lg[2]  - lse, lg[3]  - lse};
            float4 o1 = {lg[4] - lse, lg[5] - lse, lg[6]  - lse, lg[7]  - lse};
            float4 o2 = {lg[8] - lse, lg[9] - lse, lg[10] - lse, lg[11] - lse};
            ((float4*)op)[0] = o0; ((float4*)op)[1] = o1; ((float4*)op)[2] = o2;
        }
    }
}

extern "C" void kernel_launch(void* const* d_in, const int* in_sizes, int n_in,
                              void* d_out, int out_size, void* d_ws, size_t ws_size,
                              hipStream_t stream) {
    const float* sig = (const float*)d_in[0];
    const float* c1w = (const float*)d_in[1];
    const float* c1b = (const float*)d_in[2];
    const float* c2w = (const float*)d_in[3];
    const float* c2b = (const float*)d_in[4];
    const float* f1w = (const float*)d_in[5];
    const float* f1b = (const float*)d_in[6];
    const float* f2w = (const float*)d_in[7];
    const float* f2b = (const float*)d_in[8];
    const float* pw  = (const float*)d_in[9];
    const float* pb  = (const float*)d_in[10];
    float* out = (float*)d_out;

    __hip_bfloat16* W1 = (__hip_bfloat16*)d_ws;                    // [256][384] k'=o*36+t
    __hip_bfloat16* W2 = (__hip_bfloat16*)((char*)d_ws + 196608);  // [64][256]

    prep_weights<<<448, 256, 0, stream>>>(f1w, f2w, W1, W2);
    fused_kernel<<<4096, 256, 0, stream>>>(sig, c1w, c1b, c2w, c2b,
                                           W1, W2, f1b, f2b, pw, pb, out);
}